// Round 1
// baseline (398.820 us; speedup 1.0000x reference)
//
#include <hip/hip_runtime.h>
#include <hip/hip_bf16.h>

#define NT 4096
#define NE 131072
#define NB 16
#define NN 256

// ws layout (bytes)
#define OFF_DEG    0          // float[NT] -> becomes dinv in-place
#define OFF_CNT    16384      // int[NT]
#define OFF_FILL   32768      // int[NT]
#define OFF_ROWPTR 49152      // int[NT+1]
#define OFF_COL    66048      // int[NE]
#define OFF_VAL    590336     // float[NE]
#define OFF_G      1114624    // float[NT*32]
#define OFF_HA     1638912    // float[NT*32]
#define OFF_HB     2163200    // float[NT*32]
#define OFF_C      2687488    // bf16[16*32*256*256] = 64 MiB
// total = 69,796,352 bytes (~66.6 MB) of ws

// ---------------- gcn_norm setup ----------------

__global__ void k_deg(const int* __restrict__ ei, const float* __restrict__ ew,
                      float* __restrict__ deg, int* __restrict__ cnt) {
    int e = blockIdx.x * 256 + threadIdx.x;
    if (e < NE) {
        int d = ei[NE + e];            // dst = edge_index[1]
        atomicAdd(&deg[d], ew[e]);
        atomicAdd(&cnt[d], 1);
    }
}

__global__ void k_dinv(float* __restrict__ deg) {
    int n = blockIdx.x * 256 + threadIdx.x;
    if (n < NT) deg[n] = rsqrtf(deg[n] + 2.0f);   // self-loop weight 2.0; deg>0 always
}

__global__ void k_scan(const int* __restrict__ cnt, int* __restrict__ rowptr) {
    __shared__ int sums[1024];
    int t = threadIdx.x;
    int v0 = cnt[t*4], v1 = cnt[t*4+1], v2 = cnt[t*4+2], v3 = cnt[t*4+3];
    int s = v0 + v1 + v2 + v3;
    sums[t] = s;
    __syncthreads();
    for (int off = 1; off < 1024; off <<= 1) {
        int x = (t >= off) ? sums[t - off] : 0;
        __syncthreads();
        sums[t] += x;
        __syncthreads();
    }
    int excl = sums[t] - s;
    rowptr[t*4]   = excl;
    rowptr[t*4+1] = excl + v0;
    rowptr[t*4+2] = excl + v0 + v1;
    rowptr[t*4+3] = excl + v0 + v1 + v2;
    if (t == 1023) rowptr[NT] = excl + s;
}

__global__ void k_fill(const int* __restrict__ ei, const float* __restrict__ ew,
                       const float* __restrict__ dinv, const int* __restrict__ rowptr,
                       int* __restrict__ fill, int* __restrict__ col, float* __restrict__ val) {
    int e = blockIdx.x * 256 + threadIdx.x;
    if (e < NE) {
        int s = ei[e], d = ei[NE + e];
        int pos = rowptr[d] + atomicAdd(&fill[d], 1);
        col[pos] = s;
        val[pos] = dinv[s] * ew[e] * dinv[d];
    }
}

// ---------------- GCN layers ----------------

template <int CIN, int COUT>
__global__ void k_mm(const float* __restrict__ hin, const float* __restrict__ W,
                     float* __restrict__ g) {
    int tid = blockIdx.x * 256 + threadIdx.x;
    int n = tid / COUT, co = tid % COUT;
    if (n < NT) {
        float acc = 0.f;
        #pragma unroll
        for (int ci = 0; ci < CIN; ci++) acc += hin[n*CIN + ci] * W[ci*COUT + co];
        g[n*COUT + co] = acc;
    }
}

template <int COUT>
__global__ void k_agg(const float* __restrict__ g, const float* __restrict__ bias,
                      const float* __restrict__ dinv, const int* __restrict__ rowptr,
                      const int* __restrict__ col, const float* __restrict__ val,
                      float* __restrict__ hout) {
    int tid = blockIdx.x * 256 + threadIdx.x;
    int n = tid / COUT, co = tid % COUT;
    if (n < NT) {
        float dv = dinv[n];
        float acc = 2.0f * dv * dv * g[n*COUT + co];   // self loop: dinv*2.0*dinv
        int e0 = rowptr[n], e1 = rowptr[n+1];
        for (int e = e0; e < e1; e++) acc += val[e] * g[col[e]*COUT + co];
        hout[n*COUT + co] = fmaxf(acc + bias[co], 0.0f);
    }
}

// ---------------- C1: c[b,h,i,j] = relu(sum_d Wc[h,d] z[b,i,d] z[b,j,d] + bc[h]) ----------------
// block = 4 waves; wave w handles i-row (blockIdx.x*4+w); each lane holds 4 j's.

__global__ __launch_bounds__(256) void k_c1(const float* __restrict__ z,
                                            const float* __restrict__ Wc,
                                            const float* __restrict__ bc,
                                            __hip_bfloat16* __restrict__ c) {
    __shared__ float A[4][32*32];
    __shared__ float zis[4][32];
    int tid = threadIdx.x;
    int w = tid >> 6, lane = tid & 63;
    int bi = blockIdx.x * 4 + w;            // node index = b*256 + i
    int b = bi >> 8, i = bi & 255;

    if (lane < 32) zis[w][lane] = z[bi*32 + lane];
    __syncthreads();
    #pragma unroll
    for (int k = 0; k < 16; k++) {
        int idx = lane + k*64;              // 0..1023 = h*32+d
        A[w][idx] = Wc[idx] * zis[w][idx & 31];
    }
    __syncthreads();

    float zj[4][32];
    #pragma unroll
    for (int q = 0; q < 4; q++) {
        int j = lane + q*64;
        const float4* zp = (const float4*)&z[(b*256 + j)*32];
        #pragma unroll
        for (int r = 0; r < 8; r++) {
            float4 f = zp[r];
            zj[q][r*4+0] = f.x; zj[q][r*4+1] = f.y; zj[q][r*4+2] = f.z; zj[q][r*4+3] = f.w;
        }
    }

    for (int h = 0; h < 32; h++) {
        float bch = bc[h];
        float a0 = bch, a1 = bch, a2 = bch, a3 = bch;
        #pragma unroll
        for (int d = 0; d < 32; d++) {
            float av = A[w][h*32 + d];
            a0 += av * zj[0][d];
            a1 += av * zj[1][d];
            a2 += av * zj[2][d];
            a3 += av * zj[3][d];
        }
        size_t base = ((size_t)(b*32 + h) * 256 + i) * 256;
        c[base + lane      ] = __float2bfloat16(fmaxf(a0, 0.f));
        c[base + lane + 64 ] = __float2bfloat16(fmaxf(a1, 0.f));
        c[base + lane + 128] = __float2bfloat16(fmaxf(a2, 0.f));
        c[base + lane + 192] = __float2bfloat16(fmaxf(a3, 0.f));
    }
}

// ---------------- C2: 7x7 conv (32ch -> 1) + bias + sigmoid ----------------
// grid (4,8,16): j-tile 64, i-tile 32, b. 256 threads: tx=j-oct (8 px each), ty=i row.

__global__ __launch_bounds__(256) void k_conv(const __hip_bfloat16* __restrict__ c,
                                              const float* __restrict__ Wp,
                                              const float* __restrict__ bp,
                                              float* __restrict__ out) {
    __shared__ __align__(16) unsigned short tile[38*72];
    int b = blockIdx.z, i0 = blockIdx.y * 32, j0 = blockIdx.x * 64;
    int tid = threadIdx.x;
    int tx = tid & 7, ty = tid >> 3;

    float acc[8];
    #pragma unroll
    for (int p = 0; p < 8; p++) acc[p] = 0.f;

    for (int h = 0; h < 32; h++) {
        const unsigned short* cg = (const unsigned short*)c + (size_t)(b*32 + h) * 65536;
        __syncthreads();                               // protect LDS reuse
        for (int idx = tid; idx < 38*72; idx += 256) {
            int r = idx / 72, cc = idx - r*72;
            int gi = i0 - 3 + r, gj = j0 - 3 + cc;
            unsigned short v = 0;
            if (gi >= 0 && gi < 256 && gj >= 0 && gj < 256) v = cg[gi*256 + gj];
            tile[idx] = v;
        }
        __syncthreads();

        float wr[49];
        #pragma unroll
        for (int k = 0; k < 49; k++) wr[k] = Wp[h*49 + k];  // uniform -> s_loads

        #pragma unroll
        for (int di = 0; di < 7; di++) {
            const uint4* p = (const uint4*)&tile[(ty + di)*72 + tx*8];
            uint4 ua = p[0], ub = p[1];
            unsigned uu[7] = {ua.x, ua.y, ua.z, ua.w, ub.x, ub.y, ub.z};
            float win[14];
            #pragma unroll
            for (int k = 0; k < 7; k++) {
                win[2*k]   = __uint_as_float(uu[k] << 16);
                win[2*k+1] = __uint_as_float(uu[k] & 0xffff0000u);
            }
            #pragma unroll
            for (int dj = 0; dj < 7; dj++) {
                float wv = wr[di*7 + dj];
                #pragma unroll
                for (int pp = 0; pp < 8; pp++) acc[pp] += wv * win[pp + dj];
            }
        }
    }

    float bpv = bp[0];
    int i = i0 + ty, j = j0 + tx*8;
    float res[8];
    #pragma unroll
    for (int p = 0; p < 8; p++) {
        float s = acc[p] + bpv;
        res[p] = 1.0f / (1.0f + __expf(-s));
    }
    float4* op = (float4*)&out[((size_t)b*256 + i)*256 + j];
    op[0] = make_float4(res[0], res[1], res[2], res[3]);
    op[1] = make_float4(res[4], res[5], res[6], res[7]);
}

// ---------------- launch ----------------

extern "C" void kernel_launch(void* const* d_in, const int* in_sizes, int n_in,
                              void* d_out, int out_size, void* d_ws, size_t ws_size,
                              hipStream_t stream) {
    const float* x  = (const float*)d_in[0];
    const int*   ei = (const int*)d_in[1];     // (2,E) int32
    const float* ew = (const float*)d_in[2];
    // d_in[3] = batch_index (unused; reshape is contiguous)
    const float* W0 = (const float*)d_in[4];
    const float* b0 = (const float*)d_in[5];
    const float* W1 = (const float*)d_in[6];
    const float* b1 = (const float*)d_in[7];
    const float* W2 = (const float*)d_in[8];
    const float* b2 = (const float*)d_in[9];
    const float* Wc = (const float*)d_in[10];
    const float* bc = (const float*)d_in[11];
    const float* Wp = (const float*)d_in[12];
    const float* bp = (const float*)d_in[13];

    char* ws = (char*)d_ws;
    float* deg    = (float*)(ws + OFF_DEG);    // becomes dinv after k_dinv
    int*   cnt    = (int*)  (ws + OFF_CNT);
    int*   fill   = (int*)  (ws + OFF_FILL);
    int*   rowptr = (int*)  (ws + OFF_ROWPTR);
    int*   col    = (int*)  (ws + OFF_COL);
    float* val    = (float*)(ws + OFF_VAL);
    float* g      = (float*)(ws + OFF_G);
    float* hA     = (float*)(ws + OFF_HA);
    float* hB     = (float*)(ws + OFF_HB);
    __hip_bfloat16* cbuf = (__hip_bfloat16*)(ws + OFF_C);

    hipMemsetAsync(d_ws, 0, 49152, stream);    // deg + cnt + fill

    k_deg <<<NE/256, 256, 0, stream>>>(ei, ew, deg, cnt);
    k_dinv<<<NT/256, 256, 0, stream>>>(deg);
    k_scan<<<1, 1024, 0, stream>>>(cnt, rowptr);
    k_fill<<<NE/256, 256, 0, stream>>>(ei, ew, deg, rowptr, fill, col, val);

    k_mm<32,16><<<NT*16/256, 256, 0, stream>>>(x,  W0, g);
    k_agg<16>  <<<NT*16/256, 256, 0, stream>>>(g, b0, deg, rowptr, col, val, hA);
    k_mm<16,32><<<NT*32/256, 256, 0, stream>>>(hA, W1, g);
    k_agg<32>  <<<NT*32/256, 256, 0, stream>>>(g, b1, deg, rowptr, col, val, hB);
    k_mm<32,32><<<NT*32/256, 256, 0, stream>>>(hB, W2, g);
    k_agg<32>  <<<NT*32/256, 256, 0, stream>>>(g, b2, deg, rowptr, col, val, hA);

    k_c1  <<<1024, 256, 0, stream>>>(hA, Wc, bc, cbuf);
    k_conv<<<dim3(4,8,16), 256, 0, stream>>>(cbuf, Wp, bp, (float*)d_out);
}

// Round 2
// 254.776 us; speedup vs baseline: 1.5654x; 1.5654x over previous
//
#include <hip/hip_runtime.h>
#include <hip/hip_bf16.h>
#include <hip/hip_fp16.h>

#define NT 4096
#define NE 131072

// ws layout (bytes)
#define OFF_DEG    0          // float[NT] -> becomes dinv in-place
#define OFF_CNT    16384      // int[NT]
#define OFF_FILL   32768      // int[NT]
#define OFF_ROWPTR 49152      // int[NT+1]
#define OFF_COL    66048      // int[NE]
#define OFF_VAL    590336     // float[NE]
#define OFF_G      1114624    // float[NT*32]  (g0 16ch, later h3 32ch)
#define OFF_HA     1638912    // float[NT*32]  (g1)
#define OFF_HB     2163200    // float[NT*32]  (g2)
#define OFF_W2     2687488    // uint[1568] packed half2 conv weights
#define OFF_C      2695680    // f16[16*32*256*256] = 32 MiB
// total ~36.2 MB

__device__ inline unsigned int align16(unsigned int hi, unsigned int lo) {
#if __has_builtin(__builtin_amdgcn_alignbit)
    return __builtin_amdgcn_alignbit(hi, lo, 16);
#else
    return (lo >> 16) | (hi << 16);
#endif
}

// ---------------- gcn_norm setup ----------------

__global__ void k_deg(const int* __restrict__ ei, const float* __restrict__ ew,
                      float* __restrict__ deg, int* __restrict__ cnt) {
    int e = blockIdx.x * 256 + threadIdx.x;
    if (e < NE) {
        int d = ei[NE + e];
        atomicAdd(&deg[d], ew[e]);
        atomicAdd(&cnt[d], 1);
    }
}

// scan + dinv + conv-weight f16 broadcast table, one block of 1024
__global__ void k_scan(const int* __restrict__ cnt, int* __restrict__ rowptr,
                       float* __restrict__ deg, const float* __restrict__ Wp,
                       unsigned int* __restrict__ w2) {
    __shared__ int sums[1024];
    int t = threadIdx.x;
    // dinv (4 nodes/thread)
    #pragma unroll
    for (int k = 0; k < 4; k++) {
        int n = t*4 + k;
        deg[n] = rsqrtf(deg[n] + 2.0f);
    }
    // conv weights -> packed broadcast half2
    for (int k = t; k < 1568; k += 1024) {
        __half h = __float2half(Wp[k]);
        __half2 hh = __halves2half2(h, h);
        w2[k] = *(unsigned int*)&hh;
    }
    // exclusive scan of cnt
    int v0 = cnt[t*4], v1 = cnt[t*4+1], v2 = cnt[t*4+2], v3 = cnt[t*4+3];
    int s = v0 + v1 + v2 + v3;
    sums[t] = s;
    __syncthreads();
    for (int off = 1; off < 1024; off <<= 1) {
        int x = (t >= off) ? sums[t - off] : 0;
        __syncthreads();
        sums[t] += x;
        __syncthreads();
    }
    int excl = sums[t] - s;
    rowptr[t*4]   = excl;
    rowptr[t*4+1] = excl + v0;
    rowptr[t*4+2] = excl + v0 + v1;
    rowptr[t*4+3] = excl + v0 + v1 + v2;
    if (t == 1023) rowptr[NT] = excl + s;
}

__global__ void k_fill(const int* __restrict__ ei, const float* __restrict__ ew,
                       const float* __restrict__ dinv, const int* __restrict__ rowptr,
                       int* __restrict__ fill, int* __restrict__ col, float* __restrict__ val) {
    int e = blockIdx.x * 256 + threadIdx.x;
    if (e < NE) {
        int s = ei[e], d = ei[NE + e];
        int pos = rowptr[d] + atomicAdd(&fill[d], 1);
        col[pos] = s;
        val[pos] = dinv[s] * ew[e] * dinv[d];
    }
}

// ---------------- GCN ----------------

__global__ void k_mm0(const float* __restrict__ x, const float* __restrict__ W0,
                      float* __restrict__ g) {
    int tid = blockIdx.x * 256 + threadIdx.x;   // NT*16 threads
    int n = tid >> 4, co = tid & 15;
    float acc = 0.f;
    #pragma unroll
    for (int ci = 0; ci < 32; ci++) acc += x[n*32 + ci] * W0[ci*16 + co];
    g[n*16 + co] = acc;
}

// layer0 agg (16ch, edges split in 2 halves) fused with @W1 -> g1 (32ch)
__global__ __launch_bounds__(256) void k_agg0(const float* __restrict__ g,
        const float* __restrict__ bias, const float* __restrict__ W1,
        const float* __restrict__ dinv, const int* __restrict__ rowptr,
        const int* __restrict__ col, const float* __restrict__ val,
        float* __restrict__ g1) {
    __shared__ float hs[8][2][16];
    int tid = threadIdx.x;
    int nl = tid >> 5, s = tid & 31, co = s & 15, half = s >> 4;
    int n = blockIdx.x*8 + nl;
    int e0 = rowptr[n], e1 = rowptr[n+1];
    float acc = 0.f;
    if (half == 0) { float dv = dinv[n]; acc = 2.f*dv*dv*g[n*16+co]; }
    int e = e0 + half;
    for (; e + 2 < e1; e += 4) {
        int   c0 = col[e], c1 = col[e+2];
        float v0 = val[e], v1 = val[e+2];
        acc += v0 * g[c0*16+co];
        acc += v1 * g[c1*16+co];
    }
    for (; e < e1; e += 2) acc += val[e] * g[col[e]*16+co];
    hs[nl][half][co] = acc;
    __syncthreads();
    int n2 = tid >> 5, c2 = tid & 31;
    float o = 0.f;
    #pragma unroll
    for (int ci = 0; ci < 16; ci++) {
        float h = fmaxf(hs[n2][0][ci] + hs[n2][1][ci] + bias[ci], 0.f);
        o += h * W1[ci*32 + c2];
    }
    g1[(blockIdx.x*8 + n2)*32 + c2] = o;
}

// mid agg (32ch) fused with @Wnext -> gnext (32ch)
__global__ __launch_bounds__(256) void k_agg1(const float* __restrict__ g,
        const float* __restrict__ bias, const float* __restrict__ Wn,
        const float* __restrict__ dinv, const int* __restrict__ rowptr,
        const int* __restrict__ col, const float* __restrict__ val,
        float* __restrict__ gn) {
    __shared__ float hs[8][32];
    int tid = threadIdx.x;
    int nl = tid >> 5, co = tid & 31;
    int n = blockIdx.x*8 + nl;
    int e0 = rowptr[n], e1 = rowptr[n+1];
    float dv = dinv[n];
    float acc = 2.f*dv*dv*g[n*32+co];
    int e = e0;
    for (; e + 3 < e1; e += 4) {
        int   c0 = col[e], c1 = col[e+1], c2_ = col[e+2], c3 = col[e+3];
        float v0 = val[e], v1 = val[e+1], v2 = val[e+2], v3 = val[e+3];
        acc += v0 * g[c0*32+co];
        acc += v1 * g[c1*32+co];
        acc += v2 * g[c2_*32+co];
        acc += v3 * g[c3*32+co];
    }
    for (; e < e1; e++) acc += val[e] * g[col[e]*32+co];
    hs[nl][co] = acc;
    __syncthreads();
    float o = 0.f;
    #pragma unroll
    for (int ci = 0; ci < 32; ci++) {
        float h = fmaxf(hs[nl][ci] + bias[ci], 0.f);
        o += h * Wn[ci*32 + co];
    }
    gn[n*32 + co] = o;
}

// final agg (32ch) -> relu -> h3
__global__ __launch_bounds__(256) void k_agg2(const float* __restrict__ g,
        const float* __restrict__ bias,
        const float* __restrict__ dinv, const int* __restrict__ rowptr,
        const int* __restrict__ col, const float* __restrict__ val,
        float* __restrict__ h3) {
    int tid = blockIdx.x*256 + threadIdx.x;
    int n = tid >> 5, co = tid & 31;
    int e0 = rowptr[n], e1 = rowptr[n+1];
    float dv = dinv[n];
    float acc = 2.f*dv*dv*g[n*32+co];
    int e = e0;
    for (; e + 3 < e1; e += 4) {
        int   c0 = col[e], c1 = col[e+1], c2_ = col[e+2], c3 = col[e+3];
        float v0 = val[e], v1 = val[e+1], v2 = val[e+2], v3 = val[e+3];
        acc += v0 * g[c0*32+co];
        acc += v1 * g[c1*32+co];
        acc += v2 * g[c2_*32+co];
        acc += v3 * g[c3*32+co];
    }
    for (; e < e1; e++) acc += val[e] * g[col[e]*32+co];
    h3[n*32 + co] = fmaxf(acc + bias[co], 0.f);
}

// ---------------- C1: c[b,h,i,j] = relu(sum_d Wc[h,d] z[i,d] z[j,d] + bc[h]) ----------------
// 1024 blocks x 4 waves; wave = one (b,i); lane covers 4 j's. No LDS.

__global__ __launch_bounds__(256) void k_c1(const float* __restrict__ z,
                                            const float* __restrict__ Wc,
                                            const float* __restrict__ bc,
                                            __half* __restrict__ c) {
    int tid = threadIdx.x;
    int w = tid >> 6, lane = tid & 63;
    int bi = blockIdx.x * 4 + w;
    int b = bi >> 8, i = bi & 255;

    float zi[32];
    {
        const float4* zp = (const float4*)&z[bi*32];
        #pragma unroll
        for (int r = 0; r < 8; r++) {
            float4 f = zp[r];
            zi[r*4+0]=f.x; zi[r*4+1]=f.y; zi[r*4+2]=f.z; zi[r*4+3]=f.w;
        }
    }
    float zj[4][32];
    #pragma unroll
    for (int q = 0; q < 4; q++) {
        const float4* zp = (const float4*)&z[(b*256 + q*64 + lane)*32];
        #pragma unroll
        for (int r = 0; r < 8; r++) {
            float4 f = zp[r];
            zj[q][r*4+0]=f.x; zj[q][r*4+1]=f.y; zj[q][r*4+2]=f.z; zj[q][r*4+3]=f.w;
        }
    }

    for (int h = 0; h < 32; h++) {
        float a0 = 0.f, a1 = 0.f, a2 = 0.f, a3 = 0.f;
        #pragma unroll
        for (int d = 0; d < 32; d++) {
            float av = Wc[h*32 + d] * zi[d];
            a0 += av * zj[0][d];
            a1 += av * zj[1][d];
            a2 += av * zj[2][d];
            a3 += av * zj[3][d];
        }
        float bch = bc[h];
        size_t base = ((size_t)(b*32 + h) * 256 + i) * 256 + lane;
        c[base      ] = __float2half(fmaxf(a0 + bch, 0.f));
        c[base + 64 ] = __float2half(fmaxf(a1 + bch, 0.f));
        c[base + 128] = __float2half(fmaxf(a2 + bch, 0.f));
        c[base + 192] = __float2half(fmaxf(a3 + bch, 0.f));
    }
}

// ---------------- C2: 7x7 conv (32ch->1) + bias + sigmoid, packed-f16 math ----------------
// grid (4,8,16): tile j=64, i=32. 256 thr: tx=tid&7 (8 px), ty=tid>>3 (1 row).
// LDS tile rows: 38 rows x 37 used dw (74 f16), stride 40 dw, double-buffered.

__global__ __launch_bounds__(256) void k_conv(const __half* __restrict__ c,
                                              const unsigned int* __restrict__ w2,
                                              const float* __restrict__ bp,
                                              float* __restrict__ out) {
    __shared__ __align__(16) unsigned int tile[2][1520];
    int b = blockIdx.z, i0 = blockIdx.y * 32, j0 = blockIdx.x * 64;
    int tid = threadIdx.x;
    int tx = tid & 7, ty = tid >> 3;

    // precompute staging slots (6 per thread): tile col c <-> global dword j0/2-2+c
    int  goff[6]; int loff[6]; bool gok[6]; bool sok[6];
    #pragma unroll
    for (int k = 0; k < 6; k++) {
        int idx = tid + k*256;
        sok[k] = idx < 1406;                 // 38*37
        int r  = idx / 37, cc = idx - r*37;
        int gi = i0 - 3 + r;
        int gdw = (j0 >> 1) - 2 + cc;
        gok[k] = sok[k] && gi >= 0 && gi < 256 && gdw >= 0 && gdw < 128;
        goff[k] = gok[k] ? (gi*128 + gdw) : 0;
        loff[k] = r*40 + cc;
    }

    const unsigned int* cgd = (const unsigned int*)c;

    // stage h=0
    {
        const unsigned int* cp = cgd + ((size_t)(b*32 + 0) << 15);
        #pragma unroll
        for (int k = 0; k < 6; k++) {
            unsigned int v = gok[k] ? cp[goff[k]] : 0u;
            if (sok[k]) tile[0][loff[k]] = v;
        }
    }
    __syncthreads();

    __half2 acc[4];
    __half2 z2 = __float2half2_rn(0.f);
    acc[0] = z2; acc[1] = z2; acc[2] = z2; acc[3] = z2;

    for (int h = 0; h < 32; h++) {
        // issue staging loads for h+1
        unsigned int sv[6];
        if (h < 31) {
            const unsigned int* cp = cgd + ((size_t)(b*32 + h + 1) << 15);
            #pragma unroll
            for (int k = 0; k < 6; k++) sv[k] = gok[k] ? cp[goff[k]] : 0u;
        }

        const unsigned int* T = &tile[h & 1][0];
        const __half2* wrow = (const __half2*)w2 + h*49;
        int rbase = ty*40 + tx*4;
        #pragma unroll
        for (int rl = 0; rl < 7; rl++) {
            const uint4* p = (const uint4*)&T[rbase + rl*40];
            uint4 ua = p[0], ub = p[1];
            unsigned int E[8] = {ua.x, ua.y, ua.z, ua.w, ub.x, ub.y, ub.z, ub.w};
            unsigned int O[7];
            #pragma unroll
            for (int k = 0; k < 7; k++) O[k] = align16(E[k+1], E[k]);
            #pragma unroll
            for (int dj = 0; dj < 7; dj++) {
                __half2 wv = wrow[rl*7 + dj];
                #pragma unroll
                for (int p2 = 0; p2 < 4; p2++) {
                    // pair start offset = 2*p2 + dj + 1
                    unsigned int pr = (dj & 1) ? E[p2 + ((dj+1) >> 1)]
                                               : O[p2 + (dj >> 1)];
                    acc[p2] = __hfma2(wv, *(__half2*)&pr, acc[p2]);
                }
            }
        }

        if (h < 31) {
            unsigned int* Tn = &tile[(h+1) & 1][0];
            #pragma unroll
            for (int k = 0; k < 6; k++) if (sok[k]) Tn[loff[k]] = sv[k];
        }
        __syncthreads();
    }

    float bpv = bp[0];
    float res[8];
    #pragma unroll
    for (int p2 = 0; p2 < 4; p2++) {
        float2 f = __half22float2(acc[p2]);
        res[p2*2+0] = 1.0f / (1.0f + __expf(-(f.x + bpv)));
        res[p2*2+1] = 1.0f / (1.0f + __expf(-(f.y + bpv)));
    }
    float4* op = (float4*)&out[((size_t)(b*256 + i0 + ty))*256 + j0 + tx*8];
    op[0] = make_float4(res[0], res[1], res[2], res[3]);
    op[1] = make_float4(res[4], res[5], res[6], res[7]);
}

// ---------------- launch ----------------

extern "C" void kernel_launch(void* const* d_in, const int* in_sizes, int n_in,
                              void* d_out, int out_size, void* d_ws, size_t ws_size,
                              hipStream_t stream) {
    const float* x  = (const float*)d_in[0];
    const int*   ei = (const int*)d_in[1];
    const float* ew = (const float*)d_in[2];
    const float* W0 = (const float*)d_in[4];
    const float* b0 = (const float*)d_in[5];
    const float* W1 = (const float*)d_in[6];
    const float* b1 = (const float*)d_in[7];
    const float* W2 = (const float*)d_in[8];
    const float* b2 = (const float*)d_in[9];
    const float* Wc = (const float*)d_in[10];
    const float* bc = (const float*)d_in[11];
    const float* Wp = (const float*)d_in[12];
    const float* bp = (const float*)d_in[13];

    char* ws = (char*)d_ws;
    float* deg    = (float*)(ws + OFF_DEG);
    int*   cnt    = (int*)  (ws + OFF_CNT);
    int*   fill   = (int*)  (ws + OFF_FILL);
    int*   rowptr = (int*)  (ws + OFF_ROWPTR);
    int*   col    = (int*)  (ws + OFF_COL);
    float* val    = (float*)(ws + OFF_VAL);
    float* g0     = (float*)(ws + OFF_G);
    float* g1     = (float*)(ws + OFF_HA);
    float* g2     = (float*)(ws + OFF_HB);
    float* h3     = (float*)(ws + OFF_G);   // overwrites g0 (done with it)
    unsigned int* w2t = (unsigned int*)(ws + OFF_W2);
    __half* cbuf  = (__half*)(ws + OFF_C);

    hipMemsetAsync(d_ws, 0, 49152, stream);

    k_deg <<<NE/256, 256, 0, stream>>>(ei, ew, deg, cnt);
    k_scan<<<1, 1024, 0, stream>>>(cnt, rowptr, deg, Wp, w2t);
    k_fill<<<NE/256, 256, 0, stream>>>(ei, ew, deg, rowptr, fill, col, val);

    k_mm0 <<<NT*16/256, 256, 0, stream>>>(x, W0, g0);
    k_agg0<<<NT/8, 256, 0, stream>>>(g0, b0, W1, deg, rowptr, col, val, g1);
    k_agg1<<<NT/8, 256, 0, stream>>>(g1, b1, W2, deg, rowptr, col, val, g2);
    k_agg2<<<NT*32/256, 256, 0, stream>>>(g2, b2, deg, rowptr, col, val, h3);

    k_c1  <<<1024, 256, 0, stream>>>(h3, Wc, bc, cbuf);
    k_conv<<<dim3(4,8,16), 256, 0, stream>>>(cbuf, w2t, bp, (float*)d_out);
}

// Round 4
// 217.627 us; speedup vs baseline: 1.8326x; 1.1707x over previous
//
#include <hip/hip_runtime.h>
#include <hip/hip_bf16.h>
#include <hip/hip_fp16.h>

#define NT 4096
#define NE 131072

// ws layout (bytes)
#define OFF_DEG    0          // float[NT] -> becomes dinv in-place
#define OFF_CNT    16384      // int[NT]
#define OFF_FILL   32768      // int[NT]
#define OFF_ROWPTR 49152      // int[NT+1]
#define OFF_COL    66048      // int[NE]
#define OFF_VAL    590336     // float[NE]
#define OFF_G      1114624    // float[NT*32]  (g0 16ch, later h3 32ch)
#define OFF_HA     1638912    // float[NT*32]  (g1)
#define OFF_HB     2163200    // float[NT*32]  (g2)
#define OFF_W2     2687488    // uint[1568] packed half2 conv weights
#define OFF_C      2695680    // f16[16*32*256*256] = 64 MiB
// total ~69.8 MB

typedef __attribute__((ext_vector_type(8))) short bf16x8;
typedef __attribute__((ext_vector_type(4))) float f32x4;
typedef __attribute__((ext_vector_type(2))) __fp16 fp16x2;

__device__ inline unsigned int align16(unsigned int hi, unsigned int lo) {
#if __has_builtin(__builtin_amdgcn_alignbit)
    return __builtin_amdgcn_alignbit(hi, lo, 16);
#else
    return (lo >> 16) | (hi << 16);
#endif
}

__device__ inline unsigned short bfb(float x) {
    return __hip_bfloat16_raw(__float2bfloat16(x)).x;
}

// ---------------- gcn_norm setup ----------------

__global__ void k_deg(const int* __restrict__ ei, const float* __restrict__ ew,
                      float* __restrict__ deg, int* __restrict__ cnt) {
    int e = blockIdx.x * 256 + threadIdx.x;
    if (e < NE) {
        int d = ei[NE + e];
        atomicAdd(&deg[d], ew[e]);
        atomicAdd(&cnt[d], 1);
    }
}

// scan + dinv + conv-weight f16 broadcast table, one block of 1024
__global__ void k_scan(const int* __restrict__ cnt, int* __restrict__ rowptr,
                       float* __restrict__ deg, const float* __restrict__ Wp,
                       unsigned int* __restrict__ w2) {
    __shared__ int sums[1024];
    int t = threadIdx.x;
    #pragma unroll
    for (int k = 0; k < 4; k++) {
        int n = t*4 + k;
        deg[n] = rsqrtf(deg[n] + 2.0f);
    }
    for (int k = t; k < 1568; k += 1024) {
        __half h = __float2half(Wp[k]);
        __half2 hh = __halves2half2(h, h);
        w2[k] = *(unsigned int*)&hh;
    }
    int v0 = cnt[t*4], v1 = cnt[t*4+1], v2 = cnt[t*4+2], v3 = cnt[t*4+3];
    int s = v0 + v1 + v2 + v3;
    sums[t] = s;
    __syncthreads();
    for (int off = 1; off < 1024; off <<= 1) {
        int x = (t >= off) ? sums[t - off] : 0;
        __syncthreads();
        sums[t] += x;
        __syncthreads();
    }
    int excl = sums[t] - s;
    rowptr[t*4]   = excl;
    rowptr[t*4+1] = excl + v0;
    rowptr[t*4+2] = excl + v0 + v1;
    rowptr[t*4+3] = excl + v0 + v1 + v2;
    if (t == 1023) rowptr[NT] = excl + s;
}

__global__ void k_fill(const int* __restrict__ ei, const float* __restrict__ ew,
                       const float* __restrict__ dinv, const int* __restrict__ rowptr,
                       int* __restrict__ fill, int* __restrict__ col, float* __restrict__ val) {
    int e = blockIdx.x * 256 + threadIdx.x;
    if (e < NE) {
        int s = ei[e], d = ei[NE + e];
        int pos = rowptr[d] + atomicAdd(&fill[d], 1);
        col[pos] = s;
        val[pos] = dinv[s] * ew[e] * dinv[d];
    }
}

// ---------------- GCN ----------------

__global__ void k_mm0(const float* __restrict__ x, const float* __restrict__ W0,
                      float* __restrict__ g) {
    int tid = blockIdx.x * 256 + threadIdx.x;
    int n = tid >> 4, co = tid & 15;
    float acc = 0.f;
    #pragma unroll
    for (int ci = 0; ci < 32; ci++) acc += x[n*32 + ci] * W0[ci*16 + co];
    g[n*16 + co] = acc;
}

__global__ __launch_bounds__(256) void k_agg0(const float* __restrict__ g,
        const float* __restrict__ bias, const float* __restrict__ W1,
        const float* __restrict__ dinv, const int* __restrict__ rowptr,
        const int* __restrict__ col, const float* __restrict__ val,
        float* __restrict__ g1) {
    __shared__ float hs[8][2][16];
    int tid = threadIdx.x;
    int nl = tid >> 5, s = tid & 31, co = s & 15, half = s >> 4;
    int n = blockIdx.x*8 + nl;
    int e0 = rowptr[n], e1 = rowptr[n+1];
    float acc = 0.f;
    if (half == 0) { float dv = dinv[n]; acc = 2.f*dv*dv*g[n*16+co]; }
    int e = e0 + half;
    for (; e + 2 < e1; e += 4) {
        int   c0 = col[e], c1 = col[e+2];
        float v0 = val[e], v1 = val[e+2];
        acc += v0 * g[c0*16+co];
        acc += v1 * g[c1*16+co];
    }
    for (; e < e1; e += 2) acc += val[e] * g[col[e]*16+co];
    hs[nl][half][co] = acc;
    __syncthreads();
    int n2 = tid >> 5, c2 = tid & 31;
    float o = 0.f;
    #pragma unroll
    for (int ci = 0; ci < 16; ci++) {
        float h = fmaxf(hs[n2][0][ci] + hs[n2][1][ci] + bias[ci], 0.f);
        o += h * W1[ci*32 + c2];
    }
    g1[(blockIdx.x*8 + n2)*32 + c2] = o;
}

__global__ __launch_bounds__(256) void k_agg1(const float* __restrict__ g,
        const float* __restrict__ bias, const float* __restrict__ Wn,
        const float* __restrict__ dinv, const int* __restrict__ rowptr,
        const int* __restrict__ col, const float* __restrict__ val,
        float* __restrict__ gn) {
    __shared__ float hs[8][32];
    int tid = threadIdx.x;
    int nl = tid >> 5, co = tid & 31;
    int n = blockIdx.x*8 + nl;
    int e0 = rowptr[n], e1 = rowptr[n+1];
    float dv = dinv[n];
    float acc = 2.f*dv*dv*g[n*32+co];
    int e = e0;
    for (; e + 3 < e1; e += 4) {
        int   c0 = col[e], c1 = col[e+1], c2_ = col[e+2], c3 = col[e+3];
        float v0 = val[e], v1 = val[e+1], v2 = val[e+2], v3 = val[e+3];
        acc += v0 * g[c0*32+co];
        acc += v1 * g[c1*32+co];
        acc += v2 * g[c2_*32+co];
        acc += v3 * g[c3*32+co];
    }
    for (; e < e1; e++) acc += val[e] * g[col[e]*32+co];
    hs[nl][co] = acc;
    __syncthreads();
    float o = 0.f;
    #pragma unroll
    for (int ci = 0; ci < 32; ci++) {
        float h = fmaxf(hs[nl][ci] + bias[ci], 0.f);
        o += h * Wn[ci*32 + co];
    }
    gn[n*32 + co] = o;
}

__global__ __launch_bounds__(256) void k_agg2(const float* __restrict__ g,
        const float* __restrict__ bias,
        const float* __restrict__ dinv, const int* __restrict__ rowptr,
        const int* __restrict__ col, const float* __restrict__ val,
        float* __restrict__ h3) {
    int tid = blockIdx.x*256 + threadIdx.x;
    int n = tid >> 5, co = tid & 31;
    int e0 = rowptr[n], e1 = rowptr[n+1];
    float dv = dinv[n];
    float acc = 2.f*dv*dv*g[n*32+co];
    int e = e0;
    for (; e + 3 < e1; e += 4) {
        int   c0 = col[e], c1 = col[e+1], c2_ = col[e+2], c3 = col[e+3];
        float v0 = val[e], v1 = val[e+1], v2 = val[e+2], v3 = val[e+3];
        acc += v0 * g[c0*32+co];
        acc += v1 * g[c1*32+co];
        acc += v2 * g[c2_*32+co];
        acc += v3 * g[c3*32+co];
    }
    for (; e < e1; e++) acc += val[e] * g[col[e]*32+co];
    h3[n*32 + co] = fmaxf(acc + bias[co], 0.f);
}

// ---------------- C1 via MFMA: per (b,h), C = (Z diag(w_h)) Z^T, 256x256x32 ----------------
// 512 blocks (b*32+h), 4 waves. LDS: zb (bf16 Z rows) + zwb (bf16 Z*w_h rows),
// 80 B row stride (16B-aligned b128 reads, 2-way banks). Wave w: j-strips 4w..4w+3;
// per strip: 16 i-tile MFMAs (16x16x32), epilogue packs 4 j-contiguous f16 -> dwordx2.

__global__ __launch_bounds__(256) void k_c1(const float* __restrict__ z,
                                            const float* __restrict__ Wc,
                                            const float* __restrict__ bc,
                                            unsigned short* __restrict__ c) {
    __shared__ unsigned short zb[256*40];    // 20480 B
    __shared__ unsigned short zwb[256*40];   // 20480 B
    int blk = blockIdx.x;
    int b = blk >> 5, h = blk & 31;
    int tid = threadIdx.x;
    int lane = tid & 63, w = tid >> 6;
    int m = lane & 15, q = lane >> 4;

    // stage: thread t -> row t
    {
        const float4* zp = (const float4*)&z[(b*256 + tid)*32];
        const float4* wp = (const float4*)&Wc[h*32];
        unsigned int ub[16], uw[16];
        #pragma unroll
        for (int r8 = 0; r8 < 8; r8++) {
            float4 f = zp[r8];
            float4 wv = wp[r8];
            ub[r8*2]   = ((unsigned int)bfb(f.y) << 16) | bfb(f.x);
            ub[r8*2+1] = ((unsigned int)bfb(f.w) << 16) | bfb(f.z);
            uw[r8*2]   = ((unsigned int)bfb(f.y*wv.y) << 16) | bfb(f.x*wv.x);
            uw[r8*2+1] = ((unsigned int)bfb(f.w*wv.w) << 16) | bfb(f.z*wv.z);
        }
        uint4* zbp = (uint4*)&zb[tid*40];
        uint4* zwp = (uint4*)&zwb[tid*40];
        #pragma unroll
        for (int k = 0; k < 4; k++) {
            zbp[k] = ((uint4*)ub)[k];
            zwp[k] = ((uint4*)uw)[k];
        }
    }
    __syncthreads();

    // B-frags: all 16 i-tiles (lane n = m -> row i = nt*16+m, k = q*8..q*8+7)
    bf16x8 bt[16];
    #pragma unroll
    for (int nt = 0; nt < 16; nt++)
        bt[nt] = *(const bf16x8*)&zb[(nt*16 + m)*40 + q*8];

    // A-frags: 4 j-strips for this wave
    bf16x8 af[4];
    #pragma unroll
    for (int s = 0; s < 4; s++)
        af[s] = *(const bf16x8*)&zwb[((w*4 + s)*16 + m)*40 + q*8];

    float bch = bc[h];
    size_t plane = ((size_t)blk) << 16;

    #pragma unroll
    for (int s = 0; s < 4; s++) {
        f32x4 acc[16];
        #pragma unroll
        for (int nt = 0; nt < 16; nt++) {
            acc[nt] = (f32x4){0.f, 0.f, 0.f, 0.f};
            acc[nt] = __builtin_amdgcn_mfma_f32_16x16x32_bf16(af[s], bt[nt], acc[nt], 0, 0, 0);
        }
        int jbase = (w*4 + s)*16 + q*4;
        #pragma unroll
        for (int nt = 0; nt < 16; nt++) {
            float v0 = fmaxf(acc[nt][0] + bch, 0.f);
            float v1 = fmaxf(acc[nt][1] + bch, 0.f);
            float v2 = fmaxf(acc[nt][2] + bch, 0.f);
            float v3 = fmaxf(acc[nt][3] + bch, 0.f);
            fp16x2 p0 = __builtin_amdgcn_cvt_pkrtz(v0, v1);
            fp16x2 p1 = __builtin_amdgcn_cvt_pkrtz(v2, v3);
            uint2 o;
            o.x = *(unsigned int*)&p0;
            o.y = *(unsigned int*)&p1;
            *(uint2*)&c[plane + (size_t)(nt*16 + m)*256 + jbase] = o;
        }
    }
}

// ---------------- C2: 7x7 conv (32ch->1) + bias + sigmoid, packed-f16 math ----------------

__global__ __launch_bounds__(256) void k_conv(const __half* __restrict__ c,
                                              const unsigned int* __restrict__ w2,
                                              const float* __restrict__ bp,
                                              float* __restrict__ out) {
    __shared__ __align__(16) unsigned int tile[2][1520];
    int b = blockIdx.z, i0 = blockIdx.y * 32, j0 = blockIdx.x * 64;
    int tid = threadIdx.x;
    int tx = tid & 7, ty = tid >> 3;

    int  goff[6]; int loff[6]; bool gok[6]; bool sok[6];
    #pragma unroll
    for (int k = 0; k < 6; k++) {
        int idx = tid + k*256;
        sok[k] = idx < 1406;
        int r  = idx / 37, cc = idx - r*37;
        int gi = i0 - 3 + r;
        int gdw = (j0 >> 1) - 2 + cc;
        gok[k] = sok[k] && gi >= 0 && gi < 256 && gdw >= 0 && gdw < 128;
        goff[k] = gok[k] ? (gi*128 + gdw) : 0;
        loff[k] = r*40 + cc;
    }

    const unsigned int* cgd = (const unsigned int*)c;

    {
        const unsigned int* cp = cgd + ((size_t)(b*32 + 0) << 15);
        #pragma unroll
        for (int k = 0; k < 6; k++) {
            unsigned int v = gok[k] ? cp[goff[k]] : 0u;
            if (sok[k]) tile[0][loff[k]] = v;
        }
    }
    __syncthreads();

    __half2 acc[4];
    __half2 z2 = __float2half2_rn(0.f);
    acc[0] = z2; acc[1] = z2; acc[2] = z2; acc[3] = z2;

    for (int h = 0; h < 32; h++) {
        unsigned int sv[6];
        if (h < 31) {
            const unsigned int* cp = cgd + ((size_t)(b*32 + h + 1) << 15);
            #pragma unroll
            for (int k = 0; k < 6; k++) sv[k] = gok[k] ? cp[goff[k]] : 0u;
        }

        const unsigned int* T = &tile[h & 1][0];
        const __half2* wrow = (const __half2*)w2 + h*49;
        int rbase = ty*40 + tx*4;
        #pragma unroll
        for (int rl = 0; rl < 7; rl++) {
            const uint4* p = (const uint4*)&T[rbase + rl*40];
            uint4 ua = p[0], ub = p[1];
            unsigned int E[8] = {ua.x, ua.y, ua.z, ua.w, ub.x, ub.y, ub.z, ub.w};
            unsigned int O[7];
            #pragma unroll
            for (int k = 0; k < 7; k++) O[k] = align16(E[k+1], E[k]);
            #pragma unroll
            for (int dj = 0; dj < 7; dj++) {
                __half2 wv = wrow[rl*7 + dj];
                #pragma unroll
                for (int p2 = 0; p2 < 4; p2++) {
                    unsigned int pr = (dj & 1) ? E[p2 + ((dj+1) >> 1)]
                                               : O[p2 + (dj >> 1)];
                    acc[p2] = __hfma2(wv, *(__half2*)&pr, acc[p2]);
                }
            }
        }

        if (h < 31) {
            unsigned int* Tn = &tile[(h+1) & 1][0];
            #pragma unroll
            for (int k = 0; k < 6; k++) if (sok[k]) Tn[loff[k]] = sv[k];
        }
        __syncthreads();
    }

    float bpv = bp[0];
    float res[8];
    #pragma unroll
    for (int p2 = 0; p2 < 4; p2++) {
        float2 f = __half22float2(acc[p2]);
        res[p2*2+0] = 1.0f / (1.0f + __expf(-(f.x + bpv)));
        res[p2*2+1] = 1.0f / (1.0f + __expf(-(f.y + bpv)));
    }
    float4* op = (float4*)&out[((size_t)(b*256 + i0 + ty))*256 + j0 + tx*8];
    op[0] = make_float4(res[0], res[1], res[2], res[3]);
    op[1] = make_float4(res[4], res[5], res[6], res[7]);
}

// ---------------- launch ----------------

extern "C" void kernel_launch(void* const* d_in, const int* in_sizes, int n_in,
                              void* d_out, int out_size, void* d_ws, size_t ws_size,
                              hipStream_t stream) {
    const float* x  = (const float*)d_in[0];
    const int*   ei = (const int*)d_in[1];
    const float* ew = (const float*)d_in[2];
    const float* W0 = (const float*)d_in[4];
    const float* b0 = (const float*)d_in[5];
    const float* W1 = (const float*)d_in[6];
    const float* b1 = (const float*)d_in[7];
    const float* W2 = (const float*)d_in[8];
    const float* b2 = (const float*)d_in[9];
    const float* Wc = (const float*)d_in[10];
    const float* bc = (const float*)d_in[11];
    const float* Wp = (const float*)d_in[12];
    const float* bp = (const float*)d_in[13];

    char* ws = (char*)d_ws;
    float* deg    = (float*)(ws + OFF_DEG);
    int*   cnt    = (int*)  (ws + OFF_CNT);
    int*   fill   = (int*)  (ws + OFF_FILL);
    int*   rowptr = (int*)  (ws + OFF_ROWPTR);
    int*   col    = (int*)  (ws + OFF_COL);
    float* val    = (float*)(ws + OFF_VAL);
    float* g0     = (float*)(ws + OFF_G);
    float* g1     = (float*)(ws + OFF_HA);
    float* g2     = (float*)(ws + OFF_HB);
    float* h3     = (float*)(ws + OFF_G);
    unsigned int* w2t = (unsigned int*)(ws + OFF_W2);
    unsigned short* cbuf = (unsigned short*)(ws + OFF_C);

    (void)hipMemsetAsync(d_ws, 0, 49152, stream);

    k_deg <<<NE/256, 256, 0, stream>>>(ei, ew, deg, cnt);
    k_scan<<<1, 1024, 0, stream>>>(cnt, rowptr, deg, Wp, w2t);
    k_fill<<<NE/256, 256, 0, stream>>>(ei, ew, deg, rowptr, fill, col, val);

    k_mm0 <<<NT*16/256, 256, 0, stream>>>(x, W0, g0);
    k_agg0<<<NT/8, 256, 0, stream>>>(g0, b0, W1, deg, rowptr, col, val, g1);
    k_agg1<<<NT/8, 256, 0, stream>>>(g1, b1, W2, deg, rowptr, col, val, g2);
    k_agg2<<<NT*32/256, 256, 0, stream>>>(g2, b2, deg, rowptr, col, val, h3);

    k_c1  <<<512, 256, 0, stream>>>(h3, Wc, bc, cbuf);
    k_conv<<<dim3(4,8,16), 256, 0, stream>>>((const __half*)cbuf, w2t, bp, (float*)d_out);
}